// Round 6
// baseline (2176.118 us; speedup 1.0000x reference)
//
#include <hip/hip_runtime.h>

typedef __attribute__((ext_vector_type(8))) short s16x8;
typedef __attribute__((ext_vector_type(4))) float f32x4;
typedef unsigned short u16;

__device__ __forceinline__ float bu2f(u16 u) {
    union { unsigned int i; float f; } x; x.i = ((unsigned int)u) << 16; return x.f;
}
__device__ __forceinline__ u16 f2bu(float f) {
    union { float f; unsigned int i; } x; x.f = f;
    unsigned int r = x.i + 0x7fffu + ((x.i >> 16) & 1u);   // RNE
    return (u16)(r >> 16);
}

__device__ __forceinline__ void gld_lds16(const void* g, void* l) {
    __builtin_amdgcn_global_load_lds(
        (const __attribute__((address_space(1))) unsigned int*)g,
        (__attribute__((address_space(3))) unsigned int*)l, 16, 0, 0);
}
#define WAIT_LGKM0() asm volatile("s_waitcnt lgkmcnt(0)" ::: "memory")
#define MEMBAR()     asm volatile("" ::: "memory")

// ---------------------------------------------------------------- batched transpose + f32->bf16
// dst stride DS (elements); for interleaved packing pass DS=2*R with dst base offset.
__global__ __launch_bounds__(256)
void transpose4_k(const float* s0, const float* s1, const float* s2, const float* s3,
                  u16* d0, u16* d1, u16* d2, u16* d3, int R, int C, int DS) {
    const float* src = blockIdx.z == 0 ? s0 : blockIdx.z == 1 ? s1 : blockIdx.z == 2 ? s2 : s3;
    u16* dst = blockIdx.z == 0 ? d0 : blockIdx.z == 1 ? d1 : blockIdx.z == 2 ? d2 : d3;
    __shared__ u16 t[32][33];
    int bx = blockIdx.x * 32, by = blockIdx.y * 32;
    int x = bx + threadIdx.x;
#pragma unroll
    for (int k = 0; k < 4; ++k)
        t[threadIdx.y + k * 8][threadIdx.x] = f2bu(src[(size_t)(by + threadIdx.y + k * 8) * C + x]);
    __syncthreads();
    int x2 = by + threadIdx.x;
#pragma unroll
    for (int k = 0; k < 4; ++k)
        dst[(size_t)(bx + threadIdx.y + k * 8) * DS + x2] = t[threadIdx.x][threadIdx.y + k * 8];
}

// ---------------------------------------------------------------- f32 -> bf16 convert
__global__ __launch_bounds__(256)
void convert_k(const float* __restrict__ a, u16* __restrict__ o, int n4) {
    int i = blockIdx.x * 256 + threadIdx.x;
    if (i >= n4) return;
    float4 v = ((const float4*)a)[i];
    ushort4 u;
    u.x = f2bu(v.x); u.y = f2bu(v.y); u.z = f2bu(v.z); u.w = f2bu(v.w);
    ((ushort4*)o)[i] = u;
}

// ---------------------------------------------------------------- rmsnorm (row = 1024), f32 in -> bf16 out
__global__ __launch_bounds__(256)
void rmsnorm_k(const float* __restrict__ x, const float* __restrict__ g, u16* __restrict__ y) {
    const int row = blockIdx.x, tid = threadIdx.x;
    float4 v = ((const float4*)(x + (size_t)row * 1024))[tid];
    float ss = v.x * v.x + v.y * v.y + v.z * v.z + v.w * v.w;
#pragma unroll
    for (int off = 32; off; off >>= 1) ss += __shfl_xor(ss, off, 64);
    __shared__ float red[4];
    if ((tid & 63) == 0) red[tid >> 6] = ss;
    __syncthreads();
    float tot = red[0] + red[1] + red[2] + red[3];
    float sc = rsqrtf(tot * (1.f / 1024.f) + 1e-6f);
    float4 gv = ((const float4*)g)[tid];
    ushort4 o;
    o.x = f2bu(v.x * sc * gv.x);
    o.y = f2bu(v.y * sc * gv.y);
    o.z = f2bu(v.z * sc * gv.z);
    o.w = f2bu(v.w * sc * gv.w);
    ((ushort4*)(y + (size_t)row * 1024))[tid] = o;
}

// ---------------------------------------------------------------- epilogue store (shared)
__device__ __forceinline__ void gemm_store(void* __restrict__ C, const void* __restrict__ res,
                                           int N, int mode, int m, int n, float v) {
    const size_t QBSZ = (size_t)4096 * 2048;
    const size_t FSZ  = (size_t)4096 * 4096;
    if (mode == 0) {
        ((u16*)C)[(size_t)m * N + n] = f2bu(v);
    } else if (mode == 1) {
        ((u16*)C)[(size_t)m * N + n] = f2bu(v + bu2f(((const u16*)res)[(size_t)m * N + n]));
    } else if (mode == 2) {
        ((float*)C)[(size_t)m * N + n] = 2.f * v;
    } else if (mode == 4) {
        ((float*)C)[(size_t)m * N + n] = v + ((const float*)res)[(size_t)m * N + n];
    } else if (mode == 5) {
        if (n < 2048) ((u16*)C)[(size_t)m * 2048 + n] = f2bu(v);
        else if (n < 4096) ((u16*)C)[QBSZ + (size_t)m * 2048 + (n - 2048)] = f2bu(v);
        else {
            int nn = n - 4096, hh = nn >> 6, d = nn & 63, b = m >> 10, s = m & 1023;
            ((u16*)C)[2 * QBSZ + ((size_t)((b * 16 + hh) * 64 + d)) * 1024 + s] = f2bu(v);
        }
    } else if (mode == 6) {
        if (n < 2048) ((u16*)C)[(size_t)m * 2048 + n] = f2bu(v);
        else {
            int nn = n - 2048, hh = nn >> 6, d = nn & 63, b = m >> 10, s = m & 1023;
            ((u16*)C)[QBSZ + ((size_t)((b * 16 + hh) * 64 + d)) * 1024 + s] = f2bu(v);
        }
    } else {  // 7
        if (n < 4096) ((u16*)C)[(size_t)m * 4096 + n] = f2bu(v);
        else ((u16*)C)[FSZ + (size_t)m * 4096 + (n - 4096)] = f2bu(v);
    }
}

// ---------------------------------------------------------------- GEMM  C(M,N) = A(M,K) @ Bt(N,K)^T
// R3-proven: double-buffered K-loop (__syncthreads per iter), bank-conflict-free LDS
// swizzle (source chunk c0=(tid&3)^((tid>>3)&3), read slot q4^((l16>>1)&3)).
// mode 8: Bt rows interleaved [W1T;W2T] (even row = W1 col, odd = W2 col); epilogue
// pairs adjacent lanes via shfl_xor(1), computes silu(a)*b in f32, even lanes store
// to C[m][n>>1] (N/2 = 4096 columns).  Eliminates the separate silumul pass.
template <int TM>
__global__ __launch_bounds__(256, 2)
void gemm_bt(const u16* __restrict__ A, const u16* __restrict__ Bt, void* __restrict__ C,
             const void* __restrict__ res, int M, int N, int K, int mode) {
    constexpr int MI = TM / 32;
    __shared__ u16 sA[2][TM * 32];
    __shared__ u16 sB[2][128 * 32];
    const int tid = threadIdx.x;
    const int w = tid >> 6, lane = tid & 63, q4 = lane >> 4, l16 = lane & 15;
    const int m0 = blockIdx.y * TM, n0 = blockIdx.x * 128;
    const int wm = (w >> 1) * (TM / 2), wn = (w & 1) * 64;

    const f32x4 fzero = {0.f, 0.f, 0.f, 0.f};
    f32x4 acc[MI][4];
#pragma unroll
    for (int i = 0; i < MI; ++i)
#pragma unroll
        for (int j = 0; j < 4; ++j) acc[i][j] = fzero;

    const int r0 = tid >> 2;
    const int c0 = (((tid & 3) ^ ((tid >> 3) & 3)) << 3);   // swizzled source chunk (elems)

    auto stage = [&](int buf, int k0) {
        gld_lds16(A + (size_t)(m0 + r0) * K + k0 + c0, &sA[buf][tid * 8]);
        if (TM == 128)
            gld_lds16(A + (size_t)(m0 + 64 + r0) * K + k0 + c0, &sA[buf][(256 + tid) * 8]);
        gld_lds16(Bt + (size_t)(n0 + r0) * K + k0 + c0, &sB[buf][tid * 8]);
        gld_lds16(Bt + (size_t)(n0 + 64 + r0) * K + k0 + c0, &sB[buf][(256 + tid) * 8]);
    };

    const int sl = ((q4 ^ ((l16 >> 1) & 3)) << 3);          // swizzled read slot (elems)

    const int nk = K >> 5;
    stage(0, 0);
    for (int it = 0; it < nk; ++it) {
        __syncthreads();   // drains vmcnt(0): everyone's stage(it) done; buf^1 free
        if (it + 1 < nk) stage((it + 1) & 1, (it + 1) * 32);
        const int buf = it & 1;
        s16x8 af[MI], bfr[4];
#pragma unroll
        for (int i = 0; i < MI; ++i) af[i] = *(const s16x8*)&sA[buf][(wm + i * 16 + l16) * 32 + sl];
#pragma unroll
        for (int j = 0; j < 4; ++j) bfr[j] = *(const s16x8*)&sB[buf][(wn + j * 16 + l16) * 32 + sl];
#pragma unroll
        for (int i = 0; i < MI; ++i)
#pragma unroll
            for (int j = 0; j < 4; ++j)
                acc[i][j] = __builtin_amdgcn_mfma_f32_16x16x32_bf16(af[i], bfr[j], acc[i][j], 0, 0, 0);
        MEMBAR();
    }

#pragma unroll
    for (int i = 0; i < MI; ++i)
#pragma unroll
        for (int j = 0; j < 4; ++j)
#pragma unroll
            for (int r = 0; r < 4; ++r) {
                int m = m0 + wm + i * 16 + q4 * 4 + r;
                int n = n0 + wn + j * 16 + l16;
                float v = acc[i][j][r];
                if (mode == 8) {
                    float other = __shfl_xor(v, 1, 64);   // partner col (W1<->W2)
                    if (!(l16 & 1)) {
                        float prod = (v / (1.f + __expf(-v))) * other;   // silu(W1)*W2, f32
                        ((u16*)C)[(size_t)m * 4096 + (n >> 1)] = f2bu(prod);
                    }
                } else {
                    gemm_store(C, res, N, mode, m, n, v);
                }
            }
}

// ---------------------------------------------------------------- fused differential flash attention v4
template <bool CAUSAL>
__global__ __launch_bounds__(256, 2)
void diff_flash(const u16* __restrict__ Q, const u16* __restrict__ Kg, const u16* __restrict__ Vt,
                u16* __restrict__ O, const float* __restrict__ lq1, const float* __restrict__ lk1,
                const float* __restrict__ lq2, const float* __restrict__ lk2, int T, int S) {
    __shared__ u16 sK1[2][64 * 64];
    __shared__ u16 sK2[2][64 * 64];
    __shared__ u16 sV[2][64 * 64];
    __shared__ u16 sP[4][16 * 64];

    const int tid = threadIdx.x;
    const int w = tid >> 6, lane = tid & 63, q4 = lane >> 4, l16 = lane & 15;
    const int h = blockIdx.x, b = blockIdx.y;
    const int zt = CAUSAL ? (gridDim.z - 1 - blockIdx.z) : blockIdx.z;  // heavy blocks first
    const int t0 = zt * 64;
    const f32x4 fzero = {0.f, 0.f, 0.f, 0.f};

    float d1 = 0.f, d2 = 0.f;
    for (int d = 0; d < 64; ++d) {
        d1 += lq1[h * 64 + d] * lk1[h * 64 + d];
        d2 += lq2[h * 64 + d] * lk2[h * 64 + d];
    }
    const float lam = __expf(d1) - __expf(d2) + 0.8f;

    // Q fragments (B-operand: lane l16 = t, k = q4*8+j), both comps
    s16x8 qf[2][2];
    {
        const size_t qrow = (size_t)(b * T + t0 + w * 16 + l16) * 2048 + h * 128;
#pragma unroll
        for (int c = 0; c < 2; ++c)
#pragma unroll
            for (int kk = 0; kk < 2; ++kk)
                qf[c][kk] = *(const s16x8*)&Q[qrow + c * 64 + kk * 32 + q4 * 8];
    }

    f32x4 o1[4], o2[4];          // O^T accum: o[jn] rows d=jn*16+q4*4+r, col t=l16
    float ms1 = -1e30f, ls1 = 0.f, ms2 = -1e30f, ls2 = 0.f;
#pragma unroll
    for (int jn = 0; jn < 4; ++jn) { o1[jn] = fzero; o2[jn] = fzero; }

    const int ntiles = CAUSAL ? (zt + 1) : (S / 64);
    const int rk = tid >> 3;                    // staging row 0..31
    const int ckk = (((tid & 7) - rk) & 7) * 8; // rotated source chunk (elems)

    auto stage = [&](int buf, int s0) {
        const size_t kb = (size_t)(b * S + s0 + rk) * 2048 + h * 128;
        gld_lds16(&Kg[kb + ckk], &sK1[buf][tid * 8]);
        gld_lds16(&Kg[kb + (size_t)32 * 2048 + ckk], &sK1[buf][(256 + tid) * 8]);
        gld_lds16(&Kg[kb + 64 + ckk], &sK2[buf][tid * 8]);
        gld_lds16(&Kg[kb + (size_t)32 * 2048 + 64 + ckk], &sK2[buf][(256 + tid) * 8]);
        const size_t vb = (size_t)((b * 16 + h) * 64 + rk) * 1024 + s0;
        gld_lds16(&Vt[vb + ckk], &sV[buf][tid * 8]);
        gld_lds16(&Vt[vb + (size_t)32 * 1024 + ckk], &sV[buf][(256 + tid) * 8]);
    };

    u16* const sPw = sP[w];
    const int slot0 = ((0 * 4 + q4 + l16) & 7) * 8;   // read slot, kk=0
    const int slot1 = ((1 * 4 + q4 + l16) & 7) * 8;   // read slot, kk=1

    stage(0, 0);
    for (int it = 0; it < ntiles; ++it) {
        __syncthreads();   // drains vmcnt(0): everyone's stage(it) landed in LDS
        if (it + 1 < ntiles) stage((it + 1) & 1, (it + 1) * 64);
        const int buf = it & 1, s0 = it * 64;
        const bool diag = CAUSAL && (it == ntiles - 1);

        // V fragments (A-operand: lane l16 = d row), shared by both comps
        s16x8 vf[4][2];
#pragma unroll
        for (int jn = 0; jn < 4; ++jn) {
            vf[jn][0] = *(const s16x8*)&sV[buf][(jn * 16 + l16) * 64 + slot0];
            vf[jn][1] = *(const s16x8*)&sV[buf][(jn * 16 + l16) * 64 + slot1];
        }

        auto comp_step = [&](const u16* sK, const s16x8* qkk, float& m, float& l, f32x4* o) {
            f32x4 sc[4];
#pragma unroll
            for (int js = 0; js < 4; ++js) sc[js] = fzero;
#pragma unroll
            for (int js = 0; js < 4; ++js) {
                s16x8 kf0 = *(const s16x8*)&sK[(js * 16 + l16) * 64 + slot0];
                sc[js] = __builtin_amdgcn_mfma_f32_16x16x32_bf16(kf0, qkk[0], sc[js], 0, 0, 0);
                s16x8 kf1 = *(const s16x8*)&sK[(js * 16 + l16) * 64 + slot1];
                sc[js] = __builtin_amdgcn_mfma_f32_16x16x32_bf16(kf1, qkk[1], sc[js], 0, 0, 0);
            }
            float p[4][4];
#pragma unroll
            for (int js = 0; js < 4; ++js)
#pragma unroll
                for (int r = 0; r < 4; ++r) {
                    float v = sc[js][r] * 0.125f;
                    if (diag && (s0 + js * 16 + q4 * 4 + r > t0 + w * 16 + l16)) v = -1e9f;
                    p[js][r] = v;
                }
            float mx = p[0][0];
#pragma unroll
            for (int js = 0; js < 4; ++js)
#pragma unroll
                for (int r = 0; r < 4; ++r) mx = fmaxf(mx, p[js][r]);
            mx = fmaxf(mx, __shfl_xor(mx, 16, 64));
            mx = fmaxf(mx, __shfl_xor(mx, 32, 64));
            float mn = fmaxf(m, mx);
            float alpha = __expf(m - mn);
            m = mn;
            float rs = 0.f;
#pragma unroll
            for (int js = 0; js < 4; ++js)
#pragma unroll
                for (int r = 0; r < 4; ++r) { p[js][r] = __expf(p[js][r] - mn); rs += p[js][r]; }
            rs += __shfl_xor(rs, 16, 64);
            rs += __shfl_xor(rs, 32, 64);
            l = l * alpha + rs;
#pragma unroll
            for (int jn = 0; jn < 4; ++jn) o[jn] *= alpha;
            // P^T -> LDS (rotated): row t=l16, chunk = js*2+(q4>>1), half = q4&1
#pragma unroll
            for (int js = 0; js < 4; ++js) {
                ushort4 pk;
                pk.x = f2bu(p[js][0]); pk.y = f2bu(p[js][1]);
                pk.z = f2bu(p[js][2]); pk.w = f2bu(p[js][3]);
                int sl = ((js * 2 + (q4 >> 1) + l16) & 7) * 8 + (q4 & 1) * 4;
                *(ushort4*)&sPw[l16 * 64 + sl] = pk;
            }
            WAIT_LGKM0();
            s16x8 pb0 = *(const s16x8*)&sPw[l16 * 64 + slot0];
            s16x8 pb1 = *(const s16x8*)&sPw[l16 * 64 + slot1];
#pragma unroll
            for (int jn = 0; jn < 4; ++jn) {
                o[jn] = __builtin_amdgcn_mfma_f32_16x16x32_bf16(vf[jn][0], pb0, o[jn], 0, 0, 0);
                o[jn] = __builtin_amdgcn_mfma_f32_16x16x32_bf16(vf[jn][1], pb1, o[jn], 0, 0, 0);
            }
            MEMBAR();
        };
        comp_step(sK1[buf], qf[0], ms1, ls1, o1);
        comp_step(sK2[buf], qf[1], ms2, ls2, o2);
    }

    // finalize: val = o1/l1 - lam*o2/l2 (per-lane scalars), RMS over d (in-lane + 2 shuffles)
    const float inv1 = 1.f / ls1, inv2 = lam / ls2;
    float val[4][4];
    float ss = 0.f;
#pragma unroll
    for (int jn = 0; jn < 4; ++jn)
#pragma unroll
        for (int r = 0; r < 4; ++r) {
            float v = o1[jn][r] * inv1 - o2[jn][r] * inv2;
            val[jn][r] = v;
            ss += v * v;
        }
    ss += __shfl_xor(ss, 16, 64);
    ss += __shfl_xor(ss, 32, 64);
    const float scl = rsqrtf(ss * (1.f / 64.f) + 1e-6f) * 0.2f;
    const size_t orow = (size_t)(b * T + t0 + w * 16 + l16) * 1024 + h * 64;
#pragma unroll
    for (int jn = 0; jn < 4; ++jn) {
        ushort4 ov;
        ov.x = f2bu(val[jn][0] * scl); ov.y = f2bu(val[jn][1] * scl);
        ov.z = f2bu(val[jn][2] * scl); ov.w = f2bu(val[jn][3] * scl);
        *(ushort4*)&O[orow + jn * 16 + q4 * 4] = ov;
    }
}

// ---------------------------------------------------------------- launch
extern "C" void kernel_launch(void* const* d_in, const int* in_sizes, int n_in,
                              void* d_out, int out_size, void* d_ws, size_t ws_size,
                              hipStream_t stream) {
    (void)in_sizes; (void)n_in; (void)out_size; (void)ws_size;
    const float* x     = (const float*)d_in[0];
    const float* enc   = (const float*)d_in[1];
    const float* Wq_s  = (const float*)d_in[2];
    const float* Wk_s  = (const float*)d_in[3];
    const float* Wv_s  = (const float*)d_in[4];
    const float* Wo_s  = (const float*)d_in[5];
    const float* lq1_s = (const float*)d_in[6];
    const float* lk1_s = (const float*)d_in[7];
    const float* lq2_s = (const float*)d_in[8];
    const float* lk2_s = (const float*)d_in[9];
    const float* Wq_c  = (const float*)d_in[10];
    const float* Wk_c  = (const float*)d_in[11];
    const float* Wv_c  = (const float*)d_in[12];
    const float* Wo_c  = (const float*)d_in[13];
    const float* lq1_c = (const float*)d_in[14];
    const float* lk1_c = (const float*)d_in[15];
    const float* lq2_c = (const float*)d_in[16];
    const float* lk2_c = (const float*)d_in[17];
    const float* g_rms = (const float*)d_in[18];
    const float* W1    = (const float*)d_in[19];
    const float* W2    = (const float*)d_in[20];
    const float* W3    = (const float*)d_in[21];

    char* ws = (char*)d_ws;
    size_t off = 0;
    auto ab = [&](size_t elems) -> u16* { u16* p = (u16*)(ws + off); off += elems * 2; return p; };
    u16* WqkvTs = ab((size_t)5120 * 1024);   // [WqT;WkT;WvT]
    u16* WoTs   = ab((size_t)1024 * 1024);
    u16* WqTc   = ab((size_t)2048 * 1024);
    u16* WkvTc  = ab((size_t)3072 * 1024);   // [WkT;WvT]
    u16* WoTc   = ab((size_t)1024 * 1024);
    u16* W12I   = ab((size_t)8192 * 1024);   // interleaved [W1T|W2T] rows
    u16* W3T    = ab((size_t)1024 * 4096);
    char* pool = ws + off;
    u16* h0   = ab((size_t)4096 * 1024);
    u16* encb = ab((size_t)4096 * 1024);
    u16* Qb   = ab((size_t)4096 * 2048);     // Qb,Kb,Vt contiguous (mode 5/6 routing)
    u16* Kb   = ab((size_t)4096 * 2048);
    u16* Vt   = ab((size_t)4096 * 1024);
    u16* Ob   = ab((size_t)4096 * 1024);
    u16* fa   = (u16*)pool;                              // 32MB = h0+encb+Qb (dead by FFN)
    u16* h1   = ab((size_t)4096 * 1024);
    float* h2 = (float*)(ws + off); off += (size_t)4096 * 1024 * 4;
    u16* rn   = ab((size_t)4096 * 1024);

    dim3 tb(32, 8);
    transpose4_k<<<dim3(64, 32, 4), tb, 0, stream>>>(
        Wq_s, Wk_s, Wq_c, Wk_c,
        WqkvTs, WqkvTs + (size_t)2048 * 1024, WqTc, WkvTc, 1024, 2048, 1024);
    transpose4_k<<<dim3(32, 32, 4), tb, 0, stream>>>(
        Wv_s, Wo_s, Wv_c, Wo_c,
        WqkvTs + (size_t)4096 * 1024, WoTs, WkvTc + (size_t)2048 * 1024, WoTc, 1024, 1024, 1024);
    // W1/W2 interleaved: W1T row r -> W12I row 2r (base 0), W2T row r -> 2r+1 (base +1024), stride 2048
    transpose4_k<<<dim3(128, 32, 2), tb, 0, stream>>>(
        W1, W2, W1, W2, W12I, W12I + 1024, W12I, W12I, 1024, 4096, 2048);
    transpose4_k<<<dim3(32, 128, 1), tb, 0, stream>>>(W3, W3, W3, W3, W3T, W3T, W3T, W3T, 4096, 1024, 4096);

    rmsnorm_k<<<4096, 256, 0, stream>>>(x, g_rms, h0);
    convert_k<<<4096, 256, 0, stream>>>(enc, encb, 4096 * 1024 / 4);

    // self attention (causal); residual = h0 (normed input, per reference)
    gemm_bt<128><<<dim3(40, 32), 256, 0, stream>>>(h0, WqkvTs, Qb, nullptr, 4096, 5120, 1024, 5);
    diff_flash<true><<<dim3(16, 4, 16), 256, 0, stream>>>(Qb, Kb, Vt, Ob, lq1_s, lk1_s, lq2_s, lk2_s, 1024, 1024);
    gemm_bt<64><<<dim3(8, 64), 256, 0, stream>>>(Ob, WoTs, h1, h0, 4096, 1024, 1024, 1);

    // cross attention (non-causal); then h = h + h (2x folded in epilogue)
    gemm_bt<128><<<dim3(16, 32), 256, 0, stream>>>(h1, WqTc, Qb, nullptr, 4096, 2048, 1024, 0);
    gemm_bt<128><<<dim3(24, 32), 256, 0, stream>>>(encb, WkvTc, Kb, nullptr, 4096, 3072, 1024, 6);
    diff_flash<false><<<dim3(16, 4, 16), 256, 0, stream>>>(Qb, Kb, Vt, Ob, lq1_c, lk1_c, lq2_c, lk2_c, 1024, 1024);
    gemm_bt<64><<<dim3(8, 64), 256, 0, stream>>>(Ob, WoTc, h2, nullptr, 4096, 1024, 1024, 2);

    // FFN: fa = silu(rn@W1) * (rn@W2) fused in the W12 epilogue; out = fa @ W3 + h2
    rmsnorm_k<<<4096, 256, 0, stream>>>(h2, g_rms, rn);
    gemm_bt<128><<<dim3(64, 32), 256, 0, stream>>>(rn, W12I, fa, nullptr, 4096, 8192, 1024, 8);
    gemm_bt<64><<<dim3(8, 64), 256, 0, stream>>>(fa, W3T, (float*)d_out, h2, 4096, 1024, 4096, 4);
}

// Round 7
// 715.229 us; speedup vs baseline: 3.0425x; 3.0425x over previous
//
#include <hip/hip_runtime.h>

typedef __attribute__((ext_vector_type(8))) short s16x8;
typedef __attribute__((ext_vector_type(4))) float f32x4;
typedef unsigned short u16;

__device__ __forceinline__ float bu2f(u16 u) {
    union { unsigned int i; float f; } x; x.i = ((unsigned int)u) << 16; return x.f;
}
__device__ __forceinline__ u16 f2bu(float f) {
    union { float f; unsigned int i; } x; x.f = f;
    unsigned int r = x.i + 0x7fffu + ((x.i >> 16) & 1u);   // RNE
    return (u16)(r >> 16);
}

__device__ __forceinline__ void gld_lds16(const void* g, void* l) {
    __builtin_amdgcn_global_load_lds(
        (const __attribute__((address_space(1))) unsigned int*)g,
        (__attribute__((address_space(3))) unsigned int*)l, 16, 0, 0);
}
#define WAIT_LGKM0() asm volatile("s_waitcnt lgkmcnt(0)" ::: "memory")
#define MEMBAR()     asm volatile("" ::: "memory")

// ---------------------------------------------------------------- batched transpose + f32->bf16
__global__ __launch_bounds__(256)
void transpose4_k(const float* s0, const float* s1, const float* s2, const float* s3,
                  u16* d0, u16* d1, u16* d2, u16* d3, int R, int C) {
    const float* src = blockIdx.z == 0 ? s0 : blockIdx.z == 1 ? s1 : blockIdx.z == 2 ? s2 : s3;
    u16* dst = blockIdx.z == 0 ? d0 : blockIdx.z == 1 ? d1 : blockIdx.z == 2 ? d2 : d3;
    __shared__ u16 t[32][33];
    int bx = blockIdx.x * 32, by = blockIdx.y * 32;
    int x = bx + threadIdx.x;
#pragma unroll
    for (int k = 0; k < 4; ++k)
        t[threadIdx.y + k * 8][threadIdx.x] = f2bu(src[(size_t)(by + threadIdx.y + k * 8) * C + x]);
    __syncthreads();
    int x2 = by + threadIdx.x;
#pragma unroll
    for (int k = 0; k < 4; ++k)
        dst[(size_t)(bx + threadIdx.y + k * 8) * R + x2] = t[threadIdx.x][threadIdx.y + k * 8];
}

// ---------------------------------------------------------------- W1/W2 -> 16-col-group interleaved W12I
// src [1024][4096] f32; dst rows: W1 col c -> (c>>4)*32 + (c&15); W2 col c -> +16. stride 1024.
__global__ __launch_bounds__(256)
void transpose2i_k(const float* s0, const float* s1, u16* d) {
    const float* src = blockIdx.z == 0 ? s0 : s1;
    const int zoff = blockIdx.z ? 16 : 0;
    __shared__ u16 t[32][33];
    int bx = blockIdx.x * 32, by = blockIdx.y * 32;
    int x = bx + threadIdx.x;
#pragma unroll
    for (int k = 0; k < 4; ++k)
        t[threadIdx.y + k * 8][threadIdx.x] = f2bu(src[(size_t)(by + threadIdx.y + k * 8) * 4096 + x]);
    __syncthreads();
    int x2 = by + threadIdx.x;
#pragma unroll
    for (int k = 0; k < 4; ++k) {
        int c = bx + threadIdx.y + k * 8;
        int row = ((c >> 4) << 5) + (c & 15) + zoff;
        d[(size_t)row * 1024 + x2] = t[threadIdx.x][threadIdx.y + k * 8];
    }
}

// ---------------------------------------------------------------- f32 -> bf16 convert
__global__ __launch_bounds__(256)
void convert_k(const float* __restrict__ a, u16* __restrict__ o, int n4) {
    int i = blockIdx.x * 256 + threadIdx.x;
    if (i >= n4) return;
    float4 v = ((const float4*)a)[i];
    ushort4 u;
    u.x = f2bu(v.x); u.y = f2bu(v.y); u.z = f2bu(v.z); u.w = f2bu(v.w);
    ((ushort4*)o)[i] = u;
}

// ---------------------------------------------------------------- rmsnorm (row = 1024), f32 in -> bf16 out
__global__ __launch_bounds__(256)
void rmsnorm_k(const float* __restrict__ x, const float* __restrict__ g, u16* __restrict__ y) {
    const int row = blockIdx.x, tid = threadIdx.x;
    float4 v = ((const float4*)(x + (size_t)row * 1024))[tid];
    float ss = v.x * v.x + v.y * v.y + v.z * v.z + v.w * v.w;
#pragma unroll
    for (int off = 32; off; off >>= 1) ss += __shfl_xor(ss, off, 64);
    __shared__ float red[4];
    if ((tid & 63) == 0) red[tid >> 6] = ss;
    __syncthreads();
    float tot = red[0] + red[1] + red[2] + red[3];
    float sc = rsqrtf(tot * (1.f / 1024.f) + 1e-6f);
    float4 gv = ((const float4*)g)[tid];
    ushort4 o;
    o.x = f2bu(v.x * sc * gv.x);
    o.y = f2bu(v.y * sc * gv.y);
    o.z = f2bu(v.z * sc * gv.z);
    o.w = f2bu(v.w * sc * gv.w);
    ((ushort4*)(y + (size_t)row * 1024))[tid] = o;
}

// ---------------------------------------------------------------- epilogue store (shared)
__device__ __forceinline__ void gemm_store(void* __restrict__ C, const void* __restrict__ res,
                                           int N, int mode, int m, int n, float v) {
    const size_t QBSZ = (size_t)4096 * 2048;
    const size_t FSZ  = (size_t)4096 * 4096;
    if (mode == 0) {
        ((u16*)C)[(size_t)m * N + n] = f2bu(v);
    } else if (mode == 1) {
        ((u16*)C)[(size_t)m * N + n] = f2bu(v + bu2f(((const u16*)res)[(size_t)m * N + n]));
    } else if (mode == 2) {
        ((float*)C)[(size_t)m * N + n] = 2.f * v;
    } else if (mode == 4) {
        ((float*)C)[(size_t)m * N + n] = v + ((const float*)res)[(size_t)m * N + n];
    } else if (mode == 5) {
        if (n < 2048) ((u16*)C)[(size_t)m * 2048 + n] = f2bu(v);
        else if (n < 4096) ((u16*)C)[QBSZ + (size_t)m * 2048 + (n - 2048)] = f2bu(v);
        else {
            int nn = n - 4096, hh = nn >> 6, d = nn & 63, b = m >> 10, s = m & 1023;
            ((u16*)C)[2 * QBSZ + ((size_t)((b * 16 + hh) * 64 + d)) * 1024 + s] = f2bu(v);
        }
    } else if (mode == 6) {
        if (n < 2048) ((u16*)C)[(size_t)m * 2048 + n] = f2bu(v);
        else {
            int nn = n - 2048, hh = nn >> 6, d = nn & 63, b = m >> 10, s = m & 1023;
            ((u16*)C)[QBSZ + ((size_t)((b * 16 + hh) * 64 + d)) * 1024 + s] = f2bu(v);
        }
    } else {  // 7
        if (n < 4096) ((u16*)C)[(size_t)m * 4096 + n] = f2bu(v);
        else ((u16*)C)[FSZ + (size_t)m * 4096 + (n - 4096)] = f2bu(v);
    }
}

// ---------------------------------------------------------------- GEMM  C(M,N) = A(M,K) @ Bt(N,K)^T
// R3-proven loop: double-buffered (__syncthreads per iter), conflict-free LDS swizzle.
// mode 8: Bt = W12I (16-col-group interleaved). Within a wave, j-blocks alternate
// W1/W2 for the SAME 16 output columns, so silu(a)*b pairs acc[i][2jp]/acc[i][2jp+1]
// in the SAME lane; store is mode-0-shaped (all 16 lanes, consecutive u16).
template <int TM>
__global__ __launch_bounds__(256, 2)
void gemm_bt(const u16* __restrict__ A, const u16* __restrict__ Bt, void* __restrict__ C,
             const void* __restrict__ res, int M, int N, int K, int mode) {
    constexpr int MI = TM / 32;
    __shared__ u16 sA[2][TM * 32];
    __shared__ u16 sB[2][128 * 32];
    const int tid = threadIdx.x;
    const int w = tid >> 6, lane = tid & 63, q4 = lane >> 4, l16 = lane & 15;
    const int m0 = blockIdx.y * TM, n0 = blockIdx.x * 128;
    const int wm = (w >> 1) * (TM / 2), wn = (w & 1) * 64;

    const f32x4 fzero = {0.f, 0.f, 0.f, 0.f};
    f32x4 acc[MI][4];
#pragma unroll
    for (int i = 0; i < MI; ++i)
#pragma unroll
        for (int j = 0; j < 4; ++j) acc[i][j] = fzero;

    const int r0 = tid >> 2;
    const int c0 = (((tid & 3) ^ ((tid >> 3) & 3)) << 3);   // swizzled source chunk (elems)

    auto stage = [&](int buf, int k0) {
        gld_lds16(A + (size_t)(m0 + r0) * K + k0 + c0, &sA[buf][tid * 8]);
        if (TM == 128)
            gld_lds16(A + (size_t)(m0 + 64 + r0) * K + k0 + c0, &sA[buf][(256 + tid) * 8]);
        gld_lds16(Bt + (size_t)(n0 + r0) * K + k0 + c0, &sB[buf][tid * 8]);
        gld_lds16(Bt + (size_t)(n0 + 64 + r0) * K + k0 + c0, &sB[buf][(256 + tid) * 8]);
    };

    const int sl = ((q4 ^ ((l16 >> 1) & 3)) << 3);          // swizzled read slot (elems)

    const int nk = K >> 5;
    stage(0, 0);
    for (int it = 0; it < nk; ++it) {
        __syncthreads();   // drains vmcnt(0): everyone's stage(it) done; buf^1 free
        if (it + 1 < nk) stage((it + 1) & 1, (it + 1) * 32);
        const int buf = it & 1;
        s16x8 af[MI], bfr[4];
#pragma unroll
        for (int i = 0; i < MI; ++i) af[i] = *(const s16x8*)&sA[buf][(wm + i * 16 + l16) * 32 + sl];
#pragma unroll
        for (int j = 0; j < 4; ++j) bfr[j] = *(const s16x8*)&sB[buf][(wn + j * 16 + l16) * 32 + sl];
#pragma unroll
        for (int i = 0; i < MI; ++i)
#pragma unroll
            for (int j = 0; j < 4; ++j)
                acc[i][j] = __builtin_amdgcn_mfma_f32_16x16x32_bf16(af[i], bfr[j], acc[i][j], 0, 0, 0);
        MEMBAR();
    }

    if (mode == 8) {
        const int cbase = ((n0 + wn) >> 1) + l16;
#pragma unroll
        for (int i = 0; i < MI; ++i)
#pragma unroll
            for (int jp = 0; jp < 2; ++jp)
#pragma unroll
                for (int r = 0; r < 4; ++r) {
                    int m = m0 + wm + i * 16 + q4 * 4 + r;
                    float a = acc[i][jp * 2][r], b = acc[i][jp * 2 + 1][r];
                    float prod = (a / (1.f + __expf(-a))) * b;    // silu(W1)*W2, f32
                    ((u16*)C)[(size_t)m * 4096 + cbase + jp * 16] = f2bu(prod);
                }
    } else {
#pragma unroll
        for (int i = 0; i < MI; ++i)
#pragma unroll
            for (int j = 0; j < 4; ++j)
#pragma unroll
                for (int r = 0; r < 4; ++r) {
                    int m = m0 + wm + i * 16 + q4 * 4 + r;
                    int n = n0 + wn + j * 16 + l16;
                    gemm_store(C, res, N, mode, m, n, acc[i][j][r]);
                }
    }
}

// ---------------------------------------------------------------- fused differential flash attention v4
template <bool CAUSAL>
__global__ __launch_bounds__(256, 2)
void diff_flash(const u16* __restrict__ Q, const u16* __restrict__ Kg, const u16* __restrict__ Vt,
                u16* __restrict__ O, const float* __restrict__ lq1, const float* __restrict__ lk1,
                const float* __restrict__ lq2, const float* __restrict__ lk2, int T, int S) {
    __shared__ u16 sK1[2][64 * 64];
    __shared__ u16 sK2[2][64 * 64];
    __shared__ u16 sV[2][64 * 64];
    __shared__ u16 sP[4][16 * 64];

    const int tid = threadIdx.x;
    const int w = tid >> 6, lane = tid & 63, q4 = lane >> 4, l16 = lane & 15;
    const int h = blockIdx.x, b = blockIdx.y;
    const int zt = CAUSAL ? (gridDim.z - 1 - blockIdx.z) : blockIdx.z;  // heavy blocks first
    const int t0 = zt * 64;
    const f32x4 fzero = {0.f, 0.f, 0.f, 0.f};

    float d1 = 0.f, d2 = 0.f;
    for (int d = 0; d < 64; ++d) {
        d1 += lq1[h * 64 + d] * lk1[h * 64 + d];
        d2 += lq2[h * 64 + d] * lk2[h * 64 + d];
    }
    const float lam = __expf(d1) - __expf(d2) + 0.8f;

    // Q fragments (B-operand: lane l16 = t, k = q4*8+j), both comps
    s16x8 qf[2][2];
    {
        const size_t qrow = (size_t)(b * T + t0 + w * 16 + l16) * 2048 + h * 128;
#pragma unroll
        for (int c = 0; c < 2; ++c)
#pragma unroll
            for (int kk = 0; kk < 2; ++kk)
                qf[c][kk] = *(const s16x8*)&Q[qrow + c * 64 + kk * 32 + q4 * 8];
    }

    f32x4 o1[4], o2[4];          // O^T accum: o[jn] rows d=jn*16+q4*4+r, col t=l16
    float ms1 = -1e30f, ls1 = 0.f, ms2 = -1e30f, ls2 = 0.f;
#pragma unroll
    for (int jn = 0; jn < 4; ++jn) { o1[jn] = fzero; o2[jn] = fzero; }

    const int ntiles = CAUSAL ? (zt + 1) : (S / 64);
    const int rk = tid >> 3;                    // staging row 0..31
    const int ckk = (((tid & 7) - rk) & 7) * 8; // rotated source chunk (elems)

    auto stage = [&](int buf, int s0) {
        const size_t kb = (size_t)(b * S + s0 + rk) * 2048 + h * 128;
        gld_lds16(&Kg[kb + ckk], &sK1[buf][tid * 8]);
        gld_lds16(&Kg[kb + (size_t)32 * 2048 + ckk], &sK1[buf][(256 + tid) * 8]);
        gld_lds16(&Kg[kb + 64 + ckk], &sK2[buf][tid * 8]);
        gld_lds16(&Kg[kb + (size_t)32 * 2048 + 64 + ckk], &sK2[buf][(256 + tid) * 8]);
        const size_t vb = (size_t)((b * 16 + h) * 64 + rk) * 1024 + s0;
        gld_lds16(&Vt[vb + ckk], &sV[buf][tid * 8]);
        gld_lds16(&Vt[vb + (size_t)32 * 1024 + ckk], &sV[buf][(256 + tid) * 8]);
    };

    u16* const sPw = sP[w];
    const int slot0 = ((0 * 4 + q4 + l16) & 7) * 8;   // read slot, kk=0
    const int slot1 = ((1 * 4 + q4 + l16) & 7) * 8;   // read slot, kk=1

    stage(0, 0);
    for (int it = 0; it < ntiles; ++it) {
        __syncthreads();   // drains vmcnt(0): everyone's stage(it) landed in LDS
        if (it + 1 < ntiles) stage((it + 1) & 1, (it + 1) * 64);
        const int buf = it & 1, s0 = it * 64;
        const bool diag = CAUSAL && (it == ntiles - 1);

        // V fragments (A-operand: lane l16 = d row), shared by both comps
        s16x8 vf[4][2];
#pragma unroll
        for (int jn = 0; jn < 4; ++jn) {
            vf[jn][0] = *(const s16x8*)&sV[buf][(jn * 16 + l16) * 64 + slot0];
            vf[jn][1] = *(const s16x8*)&sV[buf][(jn * 16 + l16) * 64 + slot1];
        }

        auto comp_step = [&](const u16* sK, const s16x8* qkk, float& m, float& l, f32x4* o) {
            f32x4 sc[4];
#pragma unroll
            for (int js = 0; js < 4; ++js) sc[js] = fzero;
#pragma unroll
            for (int js = 0; js < 4; ++js) {
                s16x8 kf0 = *(const s16x8*)&sK[(js * 16 + l16) * 64 + slot0];
                sc[js] = __builtin_amdgcn_mfma_f32_16x16x32_bf16(kf0, qkk[0], sc[js], 0, 0, 0);
                s16x8 kf1 = *(const s16x8*)&sK[(js * 16 + l16) * 64 + slot1];
                sc[js] = __builtin_amdgcn_mfma_f32_16x16x32_bf16(kf1, qkk[1], sc[js], 0, 0, 0);
            }
            float p[4][4];
#pragma unroll
            for (int js = 0; js < 4; ++js)
#pragma unroll
                for (int r = 0; r < 4; ++r) {
                    float v = sc[js][r] * 0.125f;
                    if (diag && (s0 + js * 16 + q4 * 4 + r > t0 + w * 16 + l16)) v = -1e9f;
                    p[js][r] = v;
                }
            float mx = p[0][0];
#pragma unroll
            for (int js = 0; js < 4; ++js)
#pragma unroll
                for (int r = 0; r < 4; ++r) mx = fmaxf(mx, p[js][r]);
            mx = fmaxf(mx, __shfl_xor(mx, 16, 64));
            mx = fmaxf(mx, __shfl_xor(mx, 32, 64));
            float mn = fmaxf(m, mx);
            float alpha = __expf(m - mn);
            m = mn;
            float rs = 0.f;
#pragma unroll
            for (int js = 0; js < 4; ++js)
#pragma unroll
                for (int r = 0; r < 4; ++r) { p[js][r] = __expf(p[js][r] - mn); rs += p[js][r]; }
            rs += __shfl_xor(rs, 16, 64);
            rs += __shfl_xor(rs, 32, 64);
            l = l * alpha + rs;
#pragma unroll
            for (int jn = 0; jn < 4; ++jn) o[jn] *= alpha;
            // P^T -> LDS (rotated): row t=l16, chunk = js*2+(q4>>1), half = q4&1
#pragma unroll
            for (int js = 0; js < 4; ++js) {
                ushort4 pk;
                pk.x = f2bu(p[js][0]); pk.y = f2bu(p[js][1]);
                pk.z = f2bu(p[js][2]); pk.w = f2bu(p[js][3]);
                int sl = ((js * 2 + (q4 >> 1) + l16) & 7) * 8 + (q4 & 1) * 4;
                *(ushort4*)&sPw[l16 * 64 + sl] = pk;
            }
            WAIT_LGKM0();
            s16x8 pb0 = *(const s16x8*)&sPw[l16 * 64 + slot0];
            s16x8 pb1 = *(const s16x8*)&sPw[l16 * 64 + slot1];
#pragma unroll
            for (int jn = 0; jn < 4; ++jn) {
                o[jn] = __builtin_amdgcn_mfma_f32_16x16x32_bf16(vf[jn][0], pb0, o[jn], 0, 0, 0);
                o[jn] = __builtin_amdgcn_mfma_f32_16x16x32_bf16(vf[jn][1], pb1, o[jn], 0, 0, 0);
            }
            MEMBAR();
        };
        comp_step(sK1[buf], qf[0], ms1, ls1, o1);
        comp_step(sK2[buf], qf[1], ms2, ls2, o2);
    }

    // finalize: val = o1/l1 - lam*o2/l2 (per-lane scalars), RMS over d (in-lane + 2 shuffles)
    const float inv1 = 1.f / ls1, inv2 = lam / ls2;
    float val[4][4];
    float ss = 0.f;
#pragma unroll
    for (int jn = 0; jn < 4; ++jn)
#pragma unroll
        for (int r = 0; r < 4; ++r) {
            float v = o1[jn][r] * inv1 - o2[jn][r] * inv2;
            val[jn][r] = v;
            ss += v * v;
        }
    ss += __shfl_xor(ss, 16, 64);
    ss += __shfl_xor(ss, 32, 64);
    const float scl = rsqrtf(ss * (1.f / 64.f) + 1e-6f) * 0.2f;
    const size_t orow = (size_t)(b * T + t0 + w * 16 + l16) * 1024 + h * 64;
#pragma unroll
    for (int jn = 0; jn < 4; ++jn) {
        ushort4 ov;
        ov.x = f2bu(val[jn][0] * scl); ov.y = f2bu(val[jn][1] * scl);
        ov.z = f2bu(val[jn][2] * scl); ov.w = f2bu(val[jn][3] * scl);
        *(ushort4*)&O[orow + jn * 16 + q4 * 4] = ov;
    }
}

// ---------------------------------------------------------------- launch
extern "C" void kernel_launch(void* const* d_in, const int* in_sizes, int n_in,
                              void* d_out, int out_size, void* d_ws, size_t ws_size,
                              hipStream_t stream) {
    (void)in_sizes; (void)n_in; (void)out_size; (void)ws_size;
    const float* x     = (const float*)d_in[0];
    const float* enc   = (const float*)d_in[1];
    const float* Wq_s  = (const float*)d_in[2];
    const float* Wk_s  = (const float*)d_in[3];
    const float* Wv_s  = (const float*)d_in[4];
    const float* Wo_s  = (const float*)d_in[5];
    const float* lq1_s = (const float*)d_in[6];
    const float* lk1_s = (const float*)d_in[7];
    const float* lq2_s = (const float*)d_in[8];
    const float* lk2_s = (const float*)d_in[9];
    const float* Wq_c  = (const float*)d_in[10];
    const float* Wk_c  = (const float*)d_in[11];
    const float* Wv_c  = (const float*)d_in[12];
    const float* Wo_c  = (const float*)d_in[13];
    const float* lq1_c = (const float*)d_in[14];
    const float* lk1_c = (const float*)d_in[15];
    const float* lq2_c = (const float*)d_in[16];
    const float* lk2_c = (const float*)d_in[17];
    const float* g_rms = (const float*)d_in[18];
    const float* W1    = (const float*)d_in[19];
    const float* W2    = (const float*)d_in[20];
    const float* W3    = (const float*)d_in[21];

    char* ws = (char*)d_ws;
    size_t off = 0;
    auto ab = [&](size_t elems) -> u16* { u16* p = (u16*)(ws + off); off += elems * 2; return p; };
    u16* WqkvTs = ab((size_t)5120 * 1024);   // [WqT;WkT;WvT]
    u16* WoTs   = ab((size_t)1024 * 1024);
    u16* WqTc   = ab((size_t)2048 * 1024);
    u16* WkvTc  = ab((size_t)3072 * 1024);   // [WkT;WvT]
    u16* WoTc   = ab((size_t)1024 * 1024);
    u16* W12I   = ab((size_t)8192 * 1024);   // 16-col-group interleaved [W1T|W2T]
    u16* W3T    = ab((size_t)1024 * 4096);
    char* pool = ws + off;
    u16* h0   = ab((size_t)4096 * 1024);
    u16* encb = ab((size_t)4096 * 1024);
    u16* Qb   = ab((size_t)4096 * 2048);     // Qb,Kb,Vt contiguous (mode 5/6 routing)
    u16* Kb   = ab((size_t)4096 * 2048);
    u16* Vt   = ab((size_t)4096 * 1024);
    u16* Ob   = ab((size_t)4096 * 1024);
    u16* fa   = (u16*)pool;                              // 32MB = h0+encb+Qb (dead by FFN)
    u16* h1   = ab((size_t)4096 * 1024);
    float* h2 = (float*)(ws + off); off += (size_t)4096 * 1024 * 4;
    u16* rn   = ab((size_t)4096 * 1024);

    dim3 tb(32, 8);
    transpose4_k<<<dim3(64, 32, 4), tb, 0, stream>>>(
        Wq_s, Wk_s, Wq_c, Wk_c,
        WqkvTs, WqkvTs + (size_t)2048 * 1024, WqTc, WkvTc, 1024, 2048);
    transpose4_k<<<dim3(32, 32, 4), tb, 0, stream>>>(
        Wv_s, Wo_s, Wv_c, Wo_c,
        WqkvTs + (size_t)4096 * 1024, WoTs, WkvTc + (size_t)2048 * 1024, WoTc, 1024, 1024);
    transpose2i_k<<<dim3(128, 32, 2), tb, 0, stream>>>(W1, W2, W12I);
    transpose4_k<<<dim3(32, 128, 1), tb, 0, stream>>>(W3, W3, W3, W3, W3T, W3T, W3T, W3T, 4096, 1024);

    rmsnorm_k<<<4096, 256, 0, stream>>>(x, g_rms, h0);
    convert_k<<<4096, 256, 0, stream>>>(enc, encb, 4096 * 1024 / 4);

    // self attention (causal); residual = h0 (normed input, per reference)
    gemm_bt<128><<<dim3(40, 32), 256, 0, stream>>>(h0, WqkvTs, Qb, nullptr, 4096, 5120, 1024, 5);
    diff_flash<true><<<dim3(16, 4, 16), 256, 0, stream>>>(Qb, Kb, Vt, Ob, lq1_s, lk1_s, lq2_s, lk2_s, 1024, 1024);
    gemm_bt<64><<<dim3(8, 64), 256, 0, stream>>>(Ob, WoTs, h1, h0, 4096, 1024, 1024, 1);

    // cross attention (non-causal); then h = h + h (2x folded in epilogue)
    gemm_bt<128><<<dim3(16, 32), 256, 0, stream>>>(h1, WqTc, Qb, nullptr, 4096, 2048, 1024, 0);
    gemm_bt<128><<<dim3(24, 32), 256, 0, stream>>>(encb, WkvTc, Kb, nullptr, 4096, 3072, 1024, 6);
    diff_flash<false><<<dim3(16, 4, 16), 256, 0, stream>>>(Qb, Kb, Vt, Ob, lq1_c, lk1_c, lq2_c, lk2_c, 1024, 1024);
    gemm_bt<64><<<dim3(8, 64), 256, 0, stream>>>(Ob, WoTc, h2, nullptr, 4096, 1024, 1024, 2);

    // FFN: fa = silu(rn@W1) * (rn@W2) fused in the W12 epilogue; out = fa @ W3 + h2
    rmsnorm_k<<<4096, 256, 0, stream>>>(h2, g_rms, rn);
    gemm_bt<128><<<dim3(64, 32), 256, 0, stream>>>(rn, W12I, fa, nullptr, 4096, 8192, 1024, 8);
    gemm_bt<64><<<dim3(8, 64), 256, 0, stream>>>(fa, W3T, (float*)d_out, h2, 4096, 1024, 4096, 4);
}